// Round 1
// baseline (235.249 us; speedup 1.0000x reference)
//
#include <hip/hip_runtime.h>

// NMS 2D, 3x3 window, replicate padding, center excluded, max seeded with 0.
// x: (8, 64, 256, 256) fp32.  out[p] = x[p] if x[p] > max(0, 8 neighbors) else 0.

#define NMS_H 256
#define NMS_W 256
#define ROWS_PER_THREAD 16

struct Row6 {
    float l, v0, v1, v2, v3, r;
};

__device__ __forceinline__ Row6 load_row6(const float* __restrict__ plane, int row, int col4) {
    const float4 v = *reinterpret_cast<const float4*>(plane + row * NMS_W + col4);
    Row6 r6;
    r6.v0 = v.x; r6.v1 = v.y; r6.v2 = v.z; r6.v3 = v.w;
    // replicate-pad horizontally via clamping
    r6.l = (col4 == 0)              ? v.x : plane[row * NMS_W + col4 - 1];
    r6.r = (col4 + 4 >= NMS_W)      ? v.w : plane[row * NMS_W + col4 + 4];
    return r6;
}

__global__ __launch_bounds__(256) void nms2d_kernel(const float* __restrict__ x,
                                                    float* __restrict__ out) {
    // blockDim = (64, 4): 64 float4 column-groups cover a full row (W=256).
    // Each thread processes ROWS_PER_THREAD rows with a rolling 3-row window.
    const int plane_idx = blockIdx.x >> 2;        // 512 planes (N*C)
    const int strip     = blockIdx.x & 3;         // 4 strips of 64 rows
    const int col4      = threadIdx.x * 4;
    const int r0        = strip * 64 + threadIdx.y * ROWS_PER_THREAD;

    const float* plane  = x   + (size_t)plane_idx * (NMS_H * NMS_W);
    float*       oplane = out + (size_t)plane_idx * (NMS_H * NMS_W);

    Row6 rm = load_row6(plane, max(r0 - 1, 0), col4);   // row above (clamped)
    Row6 rc = load_row6(plane, r0, col4);               // current row

    #pragma unroll
    for (int i = 0; i < ROWS_PER_THREAD; ++i) {
        const int r = r0 + i;
        Row6 rp = load_row6(plane, min(r + 1, NMS_H - 1), col4);  // row below (clamped)

        float4 o;
        // pixel 0: horizontal window {l, v0, v1}, center = rc.v0
        {
            float m = fmaxf(0.0f, fmaxf(rm.l, fmaxf(rm.v0, rm.v1)));
            m = fmaxf(m, fmaxf(rc.l, rc.v1));
            m = fmaxf(m, fmaxf(rp.l, fmaxf(rp.v0, rp.v1)));
            o.x = (rc.v0 > m) ? rc.v0 : 0.0f;
        }
        // pixel 1: {v0, v1, v2}, center = rc.v1
        {
            float m = fmaxf(0.0f, fmaxf(rm.v0, fmaxf(rm.v1, rm.v2)));
            m = fmaxf(m, fmaxf(rc.v0, rc.v2));
            m = fmaxf(m, fmaxf(rp.v0, fmaxf(rp.v1, rp.v2)));
            o.y = (rc.v1 > m) ? rc.v1 : 0.0f;
        }
        // pixel 2: {v1, v2, v3}, center = rc.v2
        {
            float m = fmaxf(0.0f, fmaxf(rm.v1, fmaxf(rm.v2, rm.v3)));
            m = fmaxf(m, fmaxf(rc.v1, rc.v3));
            m = fmaxf(m, fmaxf(rp.v1, fmaxf(rp.v2, rp.v3)));
            o.z = (rc.v2 > m) ? rc.v2 : 0.0f;
        }
        // pixel 3: {v2, v3, r}, center = rc.v3
        {
            float m = fmaxf(0.0f, fmaxf(rm.v2, fmaxf(rm.v3, rm.r)));
            m = fmaxf(m, fmaxf(rc.v2, rc.r));
            m = fmaxf(m, fmaxf(rp.v2, fmaxf(rp.v3, rp.r)));
            o.w = (rc.v3 > m) ? rc.v3 : 0.0f;
        }

        *reinterpret_cast<float4*>(oplane + r * NMS_W + col4) = o;

        rm = rc;
        rc = rp;
    }
}

extern "C" void kernel_launch(void* const* d_in, const int* in_sizes, int n_in,
                              void* d_out, int out_size, void* d_ws, size_t ws_size,
                              hipStream_t stream) {
    const float* x = (const float*)d_in[0];
    float* out = (float*)d_out;

    // 8*64 = 512 planes, 4 row-strips each
    dim3 block(64, 4);
    dim3 grid(512 * 4);
    nms2d_kernel<<<grid, block, 0, stream>>>(x, out);
}

// Round 2
// 230.211 us; speedup vs baseline: 1.0219x; 1.0219x over previous
//
#include <hip/hip_runtime.h>

// NMS 2D, 3x3 window, replicate padding, center excluded, max seeded with 0.
// x: (8, 64, 256, 256) fp32.  out[p] = x[p] if x[p] > max(0, 8 neighbors) else 0.
//
// R2 structure: each thread owns a float4 column-group over 8 rows.
// - All 10 row loads (8 + 2 halo) issued upfront -> 10 outstanding 16B loads/lane
//   (R1 was latency-bound at 2.5 TB/s with ~1 load in flight, VGPR=24).
// - Horizontal halo from neighbor lanes via wave shuffle (wave = one full row),
//   removing the 2 scalar global loads per row.
// - Separable: per-row hmax3 computed once, reused by the rows above/below.

#define NMS_H 256
#define NMS_W 256
#define ROWS 8

typedef float f4_t __attribute__((ext_vector_type(4)));

struct RowMax {
    float4 h;   // horizontal max-of-3 per pixel (includes center)
    float4 lr;  // horizontal max of left+right only (center excluded)
};

__device__ __forceinline__ RowMax rowmax(const float4 v, const int tx) {
    float l = __shfl_up(v.w, 1, 64);    // last elem of lane tx-1
    float r = __shfl_down(v.x, 1, 64);  // first elem of lane tx+1
    if (tx == 0)  l = v.x;              // replicate pad left edge
    if (tx == 63) r = v.w;              // replicate pad right edge
    RowMax o;
    o.h.x = fmaxf(l,   fmaxf(v.x, v.y));
    o.h.y = fmaxf(v.x, fmaxf(v.y, v.z));
    o.h.z = fmaxf(v.y, fmaxf(v.z, v.w));
    o.h.w = fmaxf(v.z, fmaxf(v.w, r));
    o.lr.x = fmaxf(l,   v.y);
    o.lr.y = fmaxf(v.x, v.z);
    o.lr.z = fmaxf(v.y, v.w);
    o.lr.w = fmaxf(v.z, r);
    return o;
}

__global__ __launch_bounds__(256) void nms2d_kernel(const float* __restrict__ x,
                                                    float* __restrict__ out) {
    // blockDim = (64, 4): one wave per ty, covering one full row of float4s.
    const int plane_idx = blockIdx.x >> 3;        // 512 planes (N*C)
    const int strip     = blockIdx.x & 7;         // 8 strips of 32 rows
    const int tx        = threadIdx.x;
    const int col4      = tx * 4;
    const int r0        = strip * (ROWS * 4) + threadIdx.y * ROWS;

    const float* plane  = x   + (size_t)plane_idx * (NMS_H * NMS_W);
    float*       oplane = out + (size_t)plane_idx * (NMS_H * NMS_W);

    // Preload 8 output rows + 2 halo rows: 10 independent loads in flight.
    float4 v[ROWS + 2];
    #pragma unroll
    for (int i = 0; i < ROWS + 2; ++i) {
        const int r = min(max(r0 + i - 1, 0), NMS_H - 1);  // replicate pad vertically
        v[i] = *reinterpret_cast<const float4*>(plane + r * NMS_W + col4);
    }

    RowMax a = rowmax(v[0], tx);   // row above output row 0
    RowMax b = rowmax(v[1], tx);   // center of output row 0

    #pragma unroll
    for (int i = 0; i < ROWS; ++i) {
        RowMax c = rowmax(v[i + 2], tx);   // row below
        const float4 ctr = v[i + 1];
        float4 o;
        float m;
        m = fmaxf(0.0f, fmaxf(fmaxf(a.h.x, c.h.x), b.lr.x)); o.x = (ctr.x > m) ? ctr.x : 0.0f;
        m = fmaxf(0.0f, fmaxf(fmaxf(a.h.y, c.h.y), b.lr.y)); o.y = (ctr.y > m) ? ctr.y : 0.0f;
        m = fmaxf(0.0f, fmaxf(fmaxf(a.h.z, c.h.z), b.lr.z)); o.z = (ctr.z > m) ? ctr.z : 0.0f;
        m = fmaxf(0.0f, fmaxf(fmaxf(a.h.w, c.h.w), b.lr.w)); o.w = (ctr.w > m) ? ctr.w : 0.0f;

        f4_t ov = {o.x, o.y, o.z, o.w};
        __builtin_nontemporal_store(ov, reinterpret_cast<f4_t*>(oplane + (r0 + i) * NMS_W + col4));

        a = b; b = c;
    }
}

extern "C" void kernel_launch(void* const* d_in, const int* in_sizes, int n_in,
                              void* d_out, int out_size, void* d_ws, size_t ws_size,
                              hipStream_t stream) {
    const float* x = (const float*)d_in[0];
    float* out = (float*)d_out;

    // 8*64 = 512 planes, 8 row-strips each
    dim3 block(64, 4);
    dim3 grid(512 * 8);
    nms2d_kernel<<<grid, block, 0, stream>>>(x, out);
}

// Round 3
// 227.640 us; speedup vs baseline: 1.0334x; 1.0113x over previous
//
#include <hip/hip_runtime.h>

// NMS 2D, 3x3 window, replicate padding, center excluded, max seeded with 0.
// x: (8, 64, 256, 256) fp32.  out[p] = x[p] if x[p] > max(0, 8 neighbors) else 0.
//
// R3: flat streaming structure (shaped like the 6.6 TB/s fill kernel seen in
// rocprof). R1/R2 both stalled at 82 us / 2.6 TB/s because rolling-window
// register reuse let the compiler serialize loads (~2 outstanding/CU).
// Here each grid-stride iteration is an independent 4-row group:
//   6 independent row loads -> flat max DAG -> 4 row stores, nothing carried.

#define NMS_H 256
#define NMS_W 256
#define PLANE (NMS_H * NMS_W)
#define GROUPS_PER_PLANE (NMS_H / 4)   // 64 groups of 4 rows
#define NGROUPS (512 * GROUPS_PER_PLANE)

typedef float f4_t __attribute__((ext_vector_type(4)));

struct HV {
    float4 h;   // horizontal max-of-3 per pixel (includes center)
    float4 lr;  // horizontal max of left+right only (center excluded)
};

__device__ __forceinline__ HV rowmax(const float4 v, const int tx) {
    float l = __shfl_up(v.w, 1, 64);    // last elem of lane tx-1
    float r = __shfl_down(v.x, 1, 64);  // first elem of lane tx+1
    if (tx == 0)  l = v.x;              // replicate pad left edge
    if (tx == 63) r = v.w;              // replicate pad right edge
    HV o;
    o.h.x = fmaxf(l,   fmaxf(v.x, v.y));
    o.h.y = fmaxf(v.x, fmaxf(v.y, v.z));
    o.h.z = fmaxf(v.y, fmaxf(v.z, v.w));
    o.h.w = fmaxf(v.z, fmaxf(v.w, r));
    o.lr.x = fmaxf(l,   v.y);
    o.lr.y = fmaxf(v.x, v.z);
    o.lr.z = fmaxf(v.y, v.w);
    o.lr.w = fmaxf(v.z, r);
    return o;
}

__global__ __launch_bounds__(256) void nms2d_kernel(const float* __restrict__ x,
                                                    float* __restrict__ out) {
    // One wave (64 lanes) spans a full 256-px row as float4s.
    const int tx    = threadIdx.x;
    const int col4  = tx * 4;
    const int wave  = blockIdx.x * blockDim.y + threadIdx.y;
    const int nwave = gridDim.x * blockDim.y;

    for (int g = wave; g < NGROUPS; g += nwave) {
        const int plane_idx = g >> 6;          // / GROUPS_PER_PLANE
        const int r0        = (g & 63) * 4;    // first output row of group
        const float* pl = x   + (size_t)plane_idx * PLANE;
        float*       op = out + (size_t)plane_idx * PLANE;

        // 6 independent row loads (rows r0-1 .. r0+4, clamped) — flat batch.
        float4 v[6];
        #pragma unroll
        for (int i = 0; i < 6; ++i) {
            const int r = min(max(r0 + i - 1, 0), NMS_H - 1);
            v[i] = *reinterpret_cast<const float4*>(pl + r * NMS_W + col4);
        }

        // Per-row horizontal maxes (pure DAG, 2 shuffles per row).
        HV m[6];
        #pragma unroll
        for (int i = 0; i < 6; ++i) m[i] = rowmax(v[i], tx);

        // 4 output rows: max(0, h(above), h(below), lr(center)).
        #pragma unroll
        for (int i = 0; i < 4; ++i) {
            const float4 ctr = v[i + 1];
            const float4 ha = m[i].h, hb = m[i + 2].h, lc = m[i + 1].lr;
            f4_t o;
            float mm;
            mm = fmaxf(0.0f, fmaxf(fmaxf(ha.x, hb.x), lc.x)); o.x = (ctr.x > mm) ? ctr.x : 0.0f;
            mm = fmaxf(0.0f, fmaxf(fmaxf(ha.y, hb.y), lc.y)); o.y = (ctr.y > mm) ? ctr.y : 0.0f;
            mm = fmaxf(0.0f, fmaxf(fmaxf(ha.z, hb.z), lc.z)); o.z = (ctr.z > mm) ? ctr.z : 0.0f;
            mm = fmaxf(0.0f, fmaxf(fmaxf(ha.w, hb.w), lc.w)); o.w = (ctr.w > mm) ? ctr.w : 0.0f;
            __builtin_nontemporal_store(o, reinterpret_cast<f4_t*>(op + (r0 + i) * NMS_W + col4));
        }
    }
}

extern "C" void kernel_launch(void* const* d_in, const int* in_sizes, int n_in,
                              void* d_out, int out_size, void* d_ws, size_t ws_size,
                              hipStream_t stream) {
    const float* x = (const float*)d_in[0];
    float* out = (float*)d_out;

    // 2048 blocks x 4 waves = 8192 waves; 32768 groups -> 4 groups per wave.
    dim3 block(64, 4);
    dim3 grid(2048);
    nms2d_kernel<<<grid, block, 0, stream>>>(x, out);
}